// Round 13
// baseline (753.006 us; speedup 1.0000x reference)
//
#include <hip/hip_runtime.h>

typedef __attribute__((ext_vector_type(8))) short short8;
typedef __attribute__((ext_vector_type(4))) float f32x4;

__device__ __forceinline__ unsigned short f2bf(float f) {
  unsigned int u = __float_as_uint(f);
  u = u + 0x7FFFu + ((u >> 16) & 1u);
  return (unsigned short)(u >> 16);
}
__device__ __forceinline__ float bf2f(unsigned short b) {
  return __uint_as_float(((unsigned int)b) << 16);
}
__device__ __forceinline__ f32x4 mfma16(short8 a, short8 b, f32x4 c) {
  return __builtin_amdgcn_mfma_f32_16x16x32_bf16(a, b, c, 0, 0, 0);
}
__device__ __forceinline__ void gload_lds16(const void* g, void* l) {
  __builtin_amdgcn_global_load_lds((const __attribute__((address_space(1))) void*)g,
                                   (__attribute__((address_space(3))) void*)l, 16, 0, 0);
}
#define BAR() __builtin_amdgcn_s_barrier()
#define VM0() asm volatile("s_waitcnt vmcnt(0)" ::: "memory")

// 16-lane (DPP-row) max+argmin-col reduce stage. All VALU-latency, no LDS.
template <int CTRL>
__device__ __forceinline__ void dpp_step(float& cv, int& cc) {
  float ov = __int_as_float(
      __builtin_amdgcn_update_dpp(0, __float_as_int(cv), CTRL, 0xF, 0xF, false));
  int oc = __builtin_amdgcn_update_dpp(0, cc, CTRL, 0xF, 0xF, false);
  if (ov > cv || (ov == cv && oc < cc)) { cv = ov; cc = oc; }
}
// 16-lane DPP sum stage.
template <int CTRL>
__device__ __forceinline__ float dpp_addf(float v) {
  return v + __int_as_float(
                 __builtin_amdgcn_update_dpp(0, __float_as_int(v), CTRL, 0xF, 0xF, false));
}

// ---------------- fused weight prep: blocks 0..511 convert Wv -> bf16;
// blocks 512..515 compute wv = Wk^T bq (f32). (u_i and c terms of the expanded
// score are row-constant -> dropped: invariant for top-k AND softmax.)
__global__ __launch_bounds__(256) void prep_w_kernel(
    const float* __restrict__ Wv, unsigned short* __restrict__ Wvh,
    const float* __restrict__ Wk, const float* __restrict__ bq, float* __restrict__ wv)
{
  const int bid = (int)blockIdx.x;
  if (bid < 512) {
    long long base = ((long long)bid * 256 + threadIdx.x) * 8;
#pragma unroll
    for (int i = 0; i < 8; ++i) Wvh[base + i] = f2bf(Wv[base + i]);
  } else {
    const int h = (bid - 512) * 256 + threadIdx.x;
    float av = 0.f;
    for (int o = 0; o < 1024; ++o) av += Wk[(size_t)o * 1024 + h] * bq[o];
    wv[h] = av;
  }
}

// ---------------- Gt[a][h] = sum_o Wk[o][a] * Wq[o][h]  (exact f32 accumulate,
// 64x64 tiles), written directly as hi/lo bf16 split (no f32 round-trip).
__global__ __launch_bounds__(256) void gt_kernel(
    const float* __restrict__ Wq, const float* __restrict__ Wk,
    unsigned short* __restrict__ Gth, unsigned short* __restrict__ Gtl)
{
  __shared__ float lA[64][68], lB[64][68];
  const int tid = threadIdx.x;
  const int a0 = blockIdx.x * 64, h0 = blockIdx.y * 64;
  const int ta = tid & 15, th = tid >> 4;
  float acc[4][4];
#pragma unroll
  for (int i = 0; i < 4; ++i)
#pragma unroll
    for (int j = 0; j < 4; ++j) acc[i][j] = 0.f;
  const int orow = tid >> 2, q = tid & 3;
  for (int o0 = 0; o0 < 1024; o0 += 64) {
    __syncthreads();
#pragma unroll
    for (int i = 0; i < 4; ++i) {
      *(float4*)&lA[orow][q * 16 + i * 4] =
          *(const float4*)&Wk[(size_t)(o0 + orow) * 1024 + a0 + q * 16 + i * 4];
      *(float4*)&lB[orow][q * 16 + i * 4] =
          *(const float4*)&Wq[(size_t)(o0 + orow) * 1024 + h0 + q * 16 + i * 4];
    }
    __syncthreads();
#pragma unroll 8
    for (int o = 0; o < 64; ++o) {
      float4 av = *(const float4*)&lA[o][ta * 4];
      float4 bv = *(const float4*)&lB[o][th * 4];
      float aa[4] = {av.x, av.y, av.z, av.w}, bb[4] = {bv.x, bv.y, bv.z, bv.w};
#pragma unroll
      for (int i = 0; i < 4; ++i)
#pragma unroll
        for (int j = 0; j < 4; ++j) acc[i][j] += aa[i] * bb[j];
    }
  }
#pragma unroll
  for (int i = 0; i < 4; ++i)
#pragma unroll
    for (int j = 0; j < 4; ++j) {
      const size_t idx = (size_t)(a0 + ta * 4 + i) * 1024 + h0 + th * 4 + j;
      const float f = acc[i][j];
      const unsigned short h = f2bf(f);
      Gth[idx] = h;
      Gtl[idx] = f2bf(f - bf2f(h));
    }
}

// ---------------- x -> hi/lo bf16 split
__global__ __launch_bounds__(256) void conv_x_kernel(
    const float* __restrict__ xs, unsigned short* __restrict__ xh, unsigned short* __restrict__ xl)
{
  long long base = ((long long)blockIdx.x * 256 + threadIdx.x) * 8;
  float4 a = *(const float4*)(xs + base);
  float4 b = *(const float4*)(xs + base + 4);
  float v[8] = {a.x, a.y, a.z, a.w, b.x, b.y, b.z, b.w};
  short8 hv, lv;
#pragma unroll
  for (int i = 0; i < 8; ++i) {
    unsigned short h = f2bf(v[i]);
    hv[i] = (short)h;
    lv[i] = (short)f2bf(v[i] - bf2f(h));
  }
  *(short8*)(xh + base) = hv;
  *(short8*)(xl + base) = lv;
}

// ---------------- 256x256-tile B^T GEMM, BK=32, 8 waves, dbuf LDS (R9 proven form).
// NOTE (R10 lesson): acc = 128 f32/thread lives in the unified VGPR/AGPR file;
// min-waves > 2/SIMD forces spill (5 GB scratch traffic, MfmaUtil 7%). Keep (512,2).
// BIASMODE: 0 none, 1 row (bias[grow]), 2 col (bias[gcol], f32 add before split).
template <bool SPLIT, int BIASMODE, bool FASTA, int LGF>
__global__ __launch_bounds__(512, 2) void gemm256_kernel(
    const unsigned short* __restrict__ Aph, const unsigned short* __restrict__ Apl,
    const unsigned short* __restrict__ Bph, const unsigned short* __restrict__ Bpl,
    const float* __restrict__ bias,
    unsigned short* __restrict__ Ch, unsigned short* __restrict__ Cl,
    int lda, int ldb, int ldc)
{
  constexpr int TILES = SPLIT ? 4 : 2;
  constexpr int BUFS = TILES * 16384;
  constexpr int NP = TILES * 2;  // 16B-granule staging passes per K-tile
  __shared__ char lds[2 * BUFS];
  const int tid = threadIdx.x;
  const int wid = tid >> 6, lane = tid & 63;
  const int l = lane & 15, g = lane >> 4;
  const int wm = wid >> 2, wn = wid & 3;

  // bijective XCD-chunk swizzle (nwg % 8 == 0)
  const int nwg = gridDim.x;
  const int cpx = nwg >> 3;
  const int bid = (int)blockIdx.x;
  const int lin = (bid & 7) * cpx + (bid >> 3);
  const int tf = lin & ((1 << LGF) - 1), ts = lin >> LGF;
  const int ablk = FASTA ? tf : ts, bblk = FASTA ? ts : tf;
  const int arow0 = ablk * 256, brow0 = bblk * 256;

  // staging: pass p covers tile tp=p>>1, half h=p&1 (512 granules of 16B)
  const char* gsrc[NP];
  int ldsoff[NP];
#pragma unroll
  for (int p = 0; p < NP; ++p) {
    const int tp = p >> 1, h = p & 1;
    const int pi = h * 512 + wid * 64 + lane;
    const int row = pi >> 2;
    const int gl = (pi & 3) ^ ((row >> 1) & 3);
    const unsigned short* base =
        SPLIT ? ((tp == 0) ? Aph : (tp == 1) ? Apl : (tp == 2) ? Bph : Bpl)
              : ((tp == 0) ? Aph : Bph);
    const int r0 = (tp >= TILES / 2) ? brow0 : arow0;
    const int ld = (tp >= TILES / 2) ? ldb : lda;
    gsrc[p] = (const char*)(base + (size_t)(r0 + row) * ld + gl * 8);
    ldsoff[p] = tp * 16384 + h * 8192 + wid * 1024;
  }

  f32x4 acc[8][4];
#pragma unroll
  for (int i = 0; i < 8; ++i)
#pragma unroll
    for (int j = 0; j < 4; ++j) acc[i][j] = (f32x4){0.f, 0.f, 0.f, 0.f};

  // prologue: stage K-tile 0 into buf 0
#pragma unroll
  for (int p = 0; p < NP; ++p) gload_lds16(gsrc[p], &lds[ldsoff[p]]);
  VM0();
  BAR();

  const int nt = 32;  // K = 1024, BK = 32
#pragma unroll 1
  for (int t = 0; t < nt; ++t) {
    const int cur = (t & 1) ? BUFS : 0;
    const int nxt = BUFS - cur;
    const char* lc = lds + cur;
    const long long kadv = (long long)(t + 1) * 64;  // bytes per K-tile step

    // issue next tile's staging first (in-flight across the whole tile body)
    if (t < nt - 1) {
#pragma unroll
      for (int p = 0; p < NP; ++p) gload_lds16(gsrc[p] + kadv, &lds[nxt + ldsoff[p]]);
    }

    // flat compute on cur; compiler schedules ds_reads/MFMA interleave freely.
    short8 bh[4], bl_[4];
#pragma unroll
    for (int ni = 0; ni < 4; ++ni) {
      const int row = wn * 64 + ni * 16 + l;
      const int off = row * 64 + ((g ^ ((row >> 1) & 3)) << 4);
      bh[ni] = *(const short8*)(lc + (SPLIT ? 32768 : 16384) + off);
      if (SPLIT) bl_[ni] = *(const short8*)(lc + 49152 + off);
    }
#pragma unroll
    for (int mi = 0; mi < 8; ++mi) {
      const int row = wm * 128 + mi * 16 + l;
      const int off = row * 64 + ((g ^ ((row >> 1) & 3)) << 4);
      short8 ah = *(const short8*)(lc + off);
      short8 al_ = ah;
      if (SPLIT) al_ = *(const short8*)(lc + 16384 + off);
#pragma unroll
      for (int ni = 0; ni < 4; ++ni) {
        acc[mi][ni] = mfma16(ah, bh[ni], acc[mi][ni]);
        if (SPLIT) {
          acc[mi][ni] = mfma16(ah, bl_[ni], acc[mi][ni]);
          acc[mi][ni] = mfma16(al_, bh[ni], acc[mi][ni]);
        }
      }
    }

    VM0();  // own staging loads done; barrier makes all waves' staging visible
    BAR();
  }

#pragma unroll
  for (int mi = 0; mi < 8; ++mi)
#pragma unroll
    for (int ni = 0; ni < 4; ++ni) {
      const int gcol = brow0 + wn * 64 + ni * 16 + l;
      const int grow0v = arow0 + wm * 128 + mi * 16 + g * 4;
#pragma unroll
      for (int j = 0; j < 4; ++j) {
        const int grow = grow0v + j;
        float bv = 0.f;
        if (BIASMODE == 1) bv = bias[grow];
        if (BIASMODE == 2) bv = bias[gcol];
        float val = acc[mi][ni][j] + bv;
        unsigned short hh = f2bf(val);
        Ch[(size_t)grow * ldc + gcol] = hh;
        if (SPLIT) Cl[(size_t)grow * ldc + gcol] = f2bf(val - bf2f(hh));
      }
    }
}

// ---------------- per-window attention + FUSED LayerNorm, 64 q-rows per block.
// Score: S'_ij = Y'_i . x_j (Y' = x.G^T + wv; row-constant terms dropped).
// After PV+residual writes, block owns ALL 1024 h of its 64 rows -> LN in-block:
// per-row s/s2 accumulated in regs, DPP+LDS reduce, re-read own writes (L2-hot:
// __syncthreads drains vmcnt(0) so stores reached L2; stores don't allocate L1).
__global__ __launch_bounds__(256, 3) void attn_kernel(
    const unsigned short* __restrict__ Yh, const unsigned short* __restrict__ Yl,
    const unsigned short* __restrict__ xbh, const unsigned short* __restrict__ xbl,
    const unsigned short* __restrict__ VT, const float* __restrict__ x,
    const float* __restrict__ gamma, const float* __restrict__ beta,
    float* __restrict__ out, int Mc, int gr0)
{
  __shared__ char lds[49152];  // 2 QK bufs @0/24576; later P @0..16K, V bufs @16384/32768
  const int tid = threadIdx.x;
  const int wid = tid >> 6, lane = tid & 63;
  const int l = lane & 15, g = lane >> 4;
  const int nblk = (int)gridDim.x;  // multiple of 8
  const int bid = (int)blockIdx.x;
  const int lin = (bid & 7) * (nblk >> 3) + (bid >> 3);
  const int winid = lin >> 1, qhalf = lin & 1;
  const int qrow0 = winid * 128 + qhalf * 64;
  const int krow0 = winid * 128;

  // ---- QK staging: buf = 24KB {Yh@0(4K), Yl@4K, Kh@8K(8K), Kl@16K(8K)}
  const char* gsrc[6];
  int ldsoff[6];
  {
    const int rq = tid >> 2;
    const int slq = (tid & 3) ^ ((rq >> 1) & 3);
    gsrc[0] = (const char*)(Yh + (size_t)(qrow0 + rq) * 1024 + slq * 8);
    gsrc[1] = (const char*)(Yl + (size_t)(qrow0 + rq) * 1024 + slq * 8);
    ldsoff[0] = tid * 16;
    ldsoff[1] = 4096 + tid * 16;
#pragma unroll
    for (int kp = 0; kp < 2; ++kp) {
      const int r = kp * 64 + (tid >> 2);
      const int sl = (tid & 3) ^ ((r >> 1) & 3);
      gsrc[2 + kp] = (const char*)(xbh + (size_t)(krow0 + r) * 1024 + sl * 8);
      gsrc[4 + kp] = (const char*)(xbl + (size_t)(krow0 + r) * 1024 + sl * 8);
      ldsoff[2 + kp] = 8192 + (kp * 256 + tid) * 16;
      ldsoff[4 + kp] = 16384 + (kp * 256 + tid) * 16;
    }
  }

  f32x4 acc[8];
#pragma unroll
  for (int ni = 0; ni < 8; ++ni) acc[ni] = (f32x4){0.f, 0.f, 0.f, 0.f};

  // prologue: issue tile 0 into buf 0
#pragma unroll
  for (int p = 0; p < 6; ++p) gload_lds16(gsrc[p], lds + ldsoff[p]);

  const int qrow = wid * 16 + l;
  const int qoff = qrow * 64 + ((g ^ ((qrow >> 1) & 3)) << 4);

#pragma unroll 1
  for (int t = 0; t < 32; ++t) {
    __syncthreads();  // vmcnt(0) drain (tile t's loads, issued one tile ago) + barrier
    if (t < 31) {
      const long long adv = (long long)(t + 1) * 64;
      const int nb = ((t + 1) & 1) * 24576;
#pragma unroll
      for (int p = 0; p < 6; ++p) gload_lds16(gsrc[p] + adv, lds + nb + ldsoff[p]);
    }
    const char* cbuf = lds + (t & 1) * 24576;
    const short8 qhv = *(const short8*)(cbuf + qoff);
    const short8 qlv = *(const short8*)(cbuf + 4096 + qoff);
    __builtin_amdgcn_s_setprio(1);
#pragma unroll
    for (int ni = 0; ni < 8; ++ni) {
      const int krow = ni * 16 + l;
      const int koff = krow * 64 + ((g ^ ((krow >> 1) & 3)) << 4);
      const short8 khv = *(const short8*)(cbuf + 8192 + koff);
      const short8 klv = *(const short8*)(cbuf + 16384 + koff);
      acc[ni] = mfma16(qhv, khv, acc[ni]);
      acc[ni] = mfma16(qhv, klv, acc[ni]);
      acc[ni] = mfma16(qlv, khv, acc[ni]);
    }
    __builtin_amdgcn_s_setprio(0);
  }
  __syncthreads();  // all waves done with last QK tile -> bufs reusable

  // ---- V staging setup (dbuf 16KB chunks: 128h x 64m)
  const char* vsrc[4];
  int vdst[4];
#pragma unroll
  for (int p = 0; p < 4; ++p) {
    const int gix = p * 256 + tid;
    const int vh = gix >> 3, vsl = gix & 7;
    const int vmg = vsl ^ (vh & 7);
    vsrc[p] = (const char*)(VT + (size_t)vh * Mc + krow0 + vmg * 8);
    vdst[p] = gix * 16;
  }
  const long long hstep = (long long)Mc * 256;  // bytes per hc step (128 VT rows)

  // pre-issue V chunk 0 (hidden under top-k)
#pragma unroll
  for (int p = 0; p < 4; ++p) gload_lds16(vsrc[p], lds + 16384 + vdst[p]);

  // ---- exact top-32 + softmax
  const float s_scale = 1.0f / 32.0f;
  float vc[4][8];
  float rmax[4], ssum[4];
  unsigned int sel[4];
#pragma unroll
  for (int j = 0; j < 4; ++j) {
#pragma unroll
    for (int ni = 0; ni < 8; ++ni) vc[j][ni] = acc[ni][j] * s_scale;
    ssum[j] = 0.f;
    sel[j] = 0u;
    rmax[j] = 0.f;
  }
#pragma unroll 1
  for (int t = 0; t < 32; ++t) {
#pragma unroll
    for (int j = 0; j < 4; ++j) {
      float bv = vc[j][0];
      int bi = 0;
#pragma unroll
      for (int i = 1; i < 8; ++i)
        if (vc[j][i] > bv) { bv = vc[j][i]; bi = i; }
      float cv = bv;
      int cc = (bi << 4) | l;  // col = (bi<<4)|l; ties -> min col (matches lax.top_k)
      dpp_step<0xB1>(cv, cc);   // quad_perm(1,0,3,2): xor 1
      dpp_step<0x4E>(cv, cc);   // quad_perm(2,3,0,1): xor 2
      dpp_step<0x141>(cv, cc);  // row_half_mirror
      dpp_step<0x140>(cv, cc);  // row_mirror
      if (t == 0) rmax[j] = cv;
      ssum[j] += __expf(cv - rmax[j]);
      const bool hit = ((cc & 15) == l);
      const int ci = cc >> 4;
#pragma unroll
      for (int i = 0; i < 8; ++i)
        if (hit && ci == i) vc[j][i] = -__builtin_inff();
      sel[j] |= (hit ? (1u << ci) : 0u);
    }
  }
  // P store (bf16, swizzled) into lds[0..16K) — overwrites QK buf0 (done)
#pragma unroll
  for (int j = 0; j < 4; ++j) {
    const int qr = wid * 16 + g * 4 + j;
    const float isum = 1.0f / ssum[j];
#pragma unroll
    for (int ni = 0; ni < 8; ++ni) {
      const float p =
          ((sel[j] >> ni) & 1u) ? (__expf(acc[ni][j] * s_scale - rmax[j]) * isum) : 0.0f;
      const int col = ni * 16 + l;
      const int addr = qr * 256 + ((col * 2) ^ ((qr & 7) << 4));
      *(unsigned short*)(lds + addr) = f2bf(p);
    }
  }

  // ---- phase 2: out = P @ V over 16 chunks (8 hc x 2 mc); wave owns 32 h per chunk.
  float sacc[4][4], s2acc[4][4];
#pragma unroll
  for (int i = 0; i < 4; ++i)
#pragma unroll
    for (int j = 0; j < 4; ++j) { sacc[i][j] = 0.f; s2acc[i][j] = 0.f; }

  f32x4 a2[4][2];
#pragma unroll 1
  for (int c = 0; c < 16; ++c) {
    __syncthreads();  // drains chunk c's stage (issued one chunk ago) + flushes P (c==0)
    if (c < 15) {
      const int c1 = c + 1;
      const long long soff = (long long)(c1 >> 1) * hstep + (c1 & 1) * 128;
      const int nb = 16384 + (c1 & 1) * 16384;
#pragma unroll
      for (int p = 0; p < 4; ++p) gload_lds16(vsrc[p] + soff, lds + nb + vdst[p]);
    }
    const int mc = c & 1;
    const char* vbb = lds + 16384 + mc * 16384;
    if (mc == 0) {
#pragma unroll
      for (int i = 0; i < 4; ++i)
#pragma unroll
        for (int j = 0; j < 2; ++j) a2[i][j] = (f32x4){0.f, 0.f, 0.f, 0.f};
    }
    __builtin_amdgcn_s_setprio(1);
#pragma unroll
    for (int ks = 0; ks < 2; ++ks) {
      short8 pa[4];
#pragma unroll
      for (int mi = 0; mi < 4; ++mi) {
        const int q = mi * 16 + l;
        pa[mi] = *(const short8*)(lds + q * 256 +
                                  ((mc * 128 + ks * 64 + g * 16) ^ ((q & 7) << 4)));
      }
#pragma unroll
      for (int ni = 0; ni < 2; ++ni) {
        const int hl = wid * 32 + ni * 16 + l;
        const short8 vb =
            *(const short8*)(vbb + hl * 128 + ((ks * 64 + g * 16) ^ ((hl & 7) << 4)));
#pragma unroll
        for (int mi = 0; mi < 4; ++mi) a2[mi][ni] = mfma16(pa[mi], vb, a2[mi][ni]);
      }
    }
    __builtin_amdgcn_s_setprio(0);
    if (mc == 1) {
      const int hc = c >> 1;
#pragma unroll
      for (int mi = 0; mi < 4; ++mi)
#pragma unroll
        for (int ni = 0; ni < 2; ++ni) {
          const int h = hc * 128 + wid * 32 + ni * 16 + l;
#pragma unroll
          for (int jj = 0; jj < 4; ++jj) {
            const int q = mi * 16 + g * 4 + jj;
            float o = a2[mi][ni][jj];
            o = (o >= 0.f) ? o : 0.01f * o;
            const size_t gi = (size_t)(gr0 + qrow0 + q) * 1024 + h;
            const float val = o + x[gi];
            out[gi] = val;
            sacc[mi][jj] += val;
            s2acc[mi][jj] += val * val;
          }
        }
    }
  }

  // ---- fused LayerNorm over the block's 64 rows.
  __syncthreads();  // all PV reads of P done; LDS reusable; block's out-stores in L2
  float ws = 0.f, ws2 = 0.f;
#pragma unroll
  for (int mi = 0; mi < 4; ++mi)
#pragma unroll
    for (int jj = 0; jj < 4; ++jj) {
      float s = sacc[mi][jj], s2 = s2acc[mi][jj];
      s = dpp_addf<0xB1>(s);  s2 = dpp_addf<0xB1>(s2);
      s = dpp_addf<0x4E>(s);  s2 = dpp_addf<0x4E>(s2);
      s = dpp_addf<0x141>(s); s2 = dpp_addf<0x141>(s2);
      s = dpp_addf<0x140>(s); s2 = dpp_addf<0x140>(s2);
      if ((l >> 2) == mi && (l & 3) == jj) { ws = s; ws2 = s2; }
    }
  {
    const int row = (l >> 2) * 16 + g * 4 + (l & 3);
    float* lf = (float*)lds;
    lf[(wid * 64 + row) * 2] = ws;
    lf[(wid * 64 + row) * 2 + 1] = ws2;
  }
  __syncthreads();
  if (tid < 64) {
    float* lf = (float*)lds;
    float s = 0.f, s2 = 0.f;
#pragma unroll
    for (int w = 0; w < 4; ++w) {
      s += lf[(w * 64 + tid) * 2];
      s2 += lf[(w * 64 + tid) * 2 + 1];
    }
    const float mu = s * (1.0f / 1024.0f);
    float var = s2 * (1.0f / 1024.0f) - mu * mu;
    var = var < 0.f ? 0.f : var;
    const float rstd = 1.0f / sqrtf(var + 1e-5f);
    lf[512 + tid * 2] = mu;
    lf[512 + tid * 2 + 1] = rstd;
  }
  __syncthreads();
  const float* mur = (const float*)lds + 512;
#pragma unroll 1
  for (int hc = 0; hc < 8; ++hc) {
#pragma unroll
    for (int mi = 0; mi < 4; ++mi)
#pragma unroll
      for (int ni = 0; ni < 2; ++ni) {
        const int h = hc * 128 + wid * 32 + ni * 16 + l;
        const float gm = gamma[h], bt = beta[h];
#pragma unroll
        for (int jj = 0; jj < 4; ++jj) {
          const int q = mi * 16 + g * 4 + jj;
          const size_t gi = (size_t)(gr0 + qrow0 + q) * 1024 + h;
          const float v = out[gi];
          out[gi] = (v - mur[q * 2]) * mur[q * 2 + 1] * gm + bt;
        }
      }
  }
}

extern "C" void kernel_launch(void* const* d_in, const int* in_sizes, int n_in,
                              void* d_out, int out_size, void* d_ws, size_t ws_size,
                              hipStream_t stream)
{
  (void)in_sizes; (void)n_in; (void)out_size;
  const float* x = (const float*)d_in[0];
  const float* Wq = (const float*)d_in[1];
  const float* bq = (const float*)d_in[2];
  const float* Wk = (const float*)d_in[3];
  const float* bk = (const float*)d_in[4];
  (void)bk;
  const float* Wv = (const float*)d_in[5];
  const float* bv = (const float*)d_in[6];
  const float* gamma = (const float*)d_in[7];
  const float* beta = (const float*)d_in[8];
  float* out = (float*)d_out;

  char* ws = (char*)d_ws;
  size_t off = 0;
  auto alloc = [&](size_t n) {
    char* p = ws + off;
    off = (off + n + 255) & ~(size_t)255;
    return p;
  };
  unsigned short* Wvh = (unsigned short*)alloc(1024ull * 1024 * 2);
  unsigned short* Gth = (unsigned short*)alloc(1024ull * 1024 * 2);
  unsigned short* Gtl = (unsigned short*)alloc(1024ull * 1024 * 2);
  float* wv = (float*)alloc(1024 * 4);
  const size_t fixed = off;
  const size_t perBatch = 4096ull * 1024 * 2 * 5;  // xh,xl,Yh,Yl,VT per 4096 rows
  int NB = 8;
  while (NB > 1 && fixed + (size_t)NB * perBatch + 8192 > ws_size) NB >>= 1;
  const int M = NB * 4096;
  unsigned short* xh = (unsigned short*)alloc((size_t)M * 1024 * 2);
  unsigned short* xl = (unsigned short*)alloc((size_t)M * 1024 * 2);
  unsigned short* Yh = (unsigned short*)alloc((size_t)M * 1024 * 2);
  unsigned short* Yl = (unsigned short*)alloc((size_t)M * 1024 * 2);
  unsigned short* VT = (unsigned short*)alloc((size_t)M * 1024 * 2);

  hipLaunchKernelGGL(prep_w_kernel, dim3(516), dim3(256), 0, stream, Wv, Wvh, Wk, bq, wv);
  hipLaunchKernelGGL(gt_kernel, dim3(16, 16), dim3(256), 0, stream, Wq, Wk, Gth, Gtl);
  for (int c = 0; c < 8 / NB; ++c) {
    const int r0 = c * M;
    hipLaunchKernelGGL(conv_x_kernel, dim3(M / 2), dim3(256), 0, stream,
                       x + (size_t)r0 * 1024, xh, xl);
    // Y' = x.G^T + wv (col bias, f32 add before split)
    hipLaunchKernelGGL((gemm256_kernel<true, 2, false, 2>), dim3((M / 256) * 4), dim3(512), 0,
                       stream, xh, xl, Gth, Gtl, wv, Yh, Yl, 1024, 1024, 1024);
    // V^T: A = Wvh (1024 x 1024), B = xh (M x 1024), C = VT (1024 x M)
    hipLaunchKernelGGL((gemm256_kernel<false, 1, true, 2>), dim3(4 * (M / 256)), dim3(512), 0,
                       stream, Wvh, (const unsigned short*)nullptr, xh,
                       (const unsigned short*)nullptr, bv, VT, (unsigned short*)nullptr,
                       1024, 1024, M);
    hipLaunchKernelGGL(attn_kernel, dim3(M / 64), dim3(256), 0, stream,
                       Yh, Yl, xh, xl, VT, x, gamma, beta, out, M, r0);
  }
}

// Round 14
// 615.742 us; speedup vs baseline: 1.2229x; 1.2229x over previous
//
#include <hip/hip_runtime.h>

typedef __attribute__((ext_vector_type(8))) short short8;
typedef __attribute__((ext_vector_type(4))) float f32x4;

__device__ __forceinline__ unsigned short f2bf(float f) {
  unsigned int u = __float_as_uint(f);
  u = u + 0x7FFFu + ((u >> 16) & 1u);
  return (unsigned short)(u >> 16);
}
__device__ __forceinline__ float bf2f(unsigned short b) {
  return __uint_as_float(((unsigned int)b) << 16);
}
__device__ __forceinline__ f32x4 mfma16(short8 a, short8 b, f32x4 c) {
  return __builtin_amdgcn_mfma_f32_16x16x32_bf16(a, b, c, 0, 0, 0);
}
__device__ __forceinline__ void gload_lds16(const void* g, void* l) {
  __builtin_amdgcn_global_load_lds((const __attribute__((address_space(1))) void*)g,
                                   (__attribute__((address_space(3))) void*)l, 16, 0, 0);
}
#define BAR() __builtin_amdgcn_s_barrier()
#define VM0() asm volatile("s_waitcnt vmcnt(0)" ::: "memory")

// 16-lane (DPP-row) max+argmin-col reduce stage. All VALU-latency, no LDS.
template <int CTRL>
__device__ __forceinline__ void dpp_step(float& cv, int& cc) {
  float ov = __int_as_float(
      __builtin_amdgcn_update_dpp(0, __float_as_int(cv), CTRL, 0xF, 0xF, false));
  int oc = __builtin_amdgcn_update_dpp(0, cc, CTRL, 0xF, 0xF, false);
  if (ov > cv || (ov == cv && oc < cc)) { cv = ov; cc = oc; }
}

// ---------------- Wv -> bf16
__global__ __launch_bounds__(256) void conv_wv_kernel(
    const float* __restrict__ Wv, unsigned short* __restrict__ Wvh)
{
  long long base = ((long long)blockIdx.x * 256 + threadIdx.x) * 8;
#pragma unroll
  for (int i = 0; i < 8; ++i) Wvh[base + i] = f2bf(Wv[base + i]);
}

// ---------------- wv = Wk^T bq (f32). (u_i and c are row-constant in S -> dropped:
// they shift all 128 scores of a row equally, invariant for top-k AND softmax.)
__global__ __launch_bounds__(256) void wv_kernel(
    const float* __restrict__ Wk, const float* __restrict__ bq, float* __restrict__ wv)
{
  const int h = blockIdx.x * 256 + threadIdx.x;
  float av = 0.f;
  for (int o = 0; o < 1024; ++o) av += Wk[(size_t)o * 1024 + h] * bq[o];
  wv[h] = av;
}

// ---------------- Gt[a][h] = sum_o Wk[o][a] * Wq[o][h]  (exact f32, 64x64 tiles)
__global__ __launch_bounds__(256) void gt_kernel(
    const float* __restrict__ Wq, const float* __restrict__ Wk, float* __restrict__ Gt)
{
  __shared__ float lA[64][68], lB[64][68];
  const int tid = threadIdx.x;
  const int a0 = blockIdx.x * 64, h0 = blockIdx.y * 64;
  const int ta = tid & 15, th = tid >> 4;
  float acc[4][4];
#pragma unroll
  for (int i = 0; i < 4; ++i)
#pragma unroll
    for (int j = 0; j < 4; ++j) acc[i][j] = 0.f;
  const int orow = tid >> 2, q = tid & 3;
  for (int o0 = 0; o0 < 1024; o0 += 64) {
    __syncthreads();
#pragma unroll
    for (int i = 0; i < 4; ++i) {
      *(float4*)&lA[orow][q * 16 + i * 4] =
          *(const float4*)&Wk[(size_t)(o0 + orow) * 1024 + a0 + q * 16 + i * 4];
      *(float4*)&lB[orow][q * 16 + i * 4] =
          *(const float4*)&Wq[(size_t)(o0 + orow) * 1024 + h0 + q * 16 + i * 4];
    }
    __syncthreads();
#pragma unroll 8
    for (int o = 0; o < 64; ++o) {
      float4 av = *(const float4*)&lA[o][ta * 4];
      float4 bv = *(const float4*)&lB[o][th * 4];
      float aa[4] = {av.x, av.y, av.z, av.w}, bb[4] = {bv.x, bv.y, bv.z, bv.w};
#pragma unroll
      for (int i = 0; i < 4; ++i)
#pragma unroll
        for (int j = 0; j < 4; ++j) acc[i][j] += aa[i] * bb[j];
    }
  }
#pragma unroll
  for (int i = 0; i < 4; ++i)
#pragma unroll
    for (int j = 0; j < 4; ++j)
      Gt[(size_t)(a0 + ta * 4 + i) * 1024 + h0 + th * 4 + j] = acc[i][j];
}

// ---------------- Gt f32 -> hi/lo bf16 split
__global__ __launch_bounds__(256) void gsplit_kernel(
    const float* __restrict__ Gt, unsigned short* __restrict__ Gth,
    unsigned short* __restrict__ Gtl)
{
  long long base = ((long long)blockIdx.x * 256 + threadIdx.x) * 8;
#pragma unroll
  for (int i = 0; i < 8; ++i) {
    float f = Gt[base + i];
    unsigned short h = f2bf(f);
    Gth[base + i] = h;
    Gtl[base + i] = f2bf(f - bf2f(h));
  }
}

// ---------------- x -> hi/lo bf16 split
__global__ __launch_bounds__(256) void conv_x_kernel(
    const float* __restrict__ xs, unsigned short* __restrict__ xh, unsigned short* __restrict__ xl)
{
  long long base = ((long long)blockIdx.x * 256 + threadIdx.x) * 8;
  float4 a = *(const float4*)(xs + base);
  float4 b = *(const float4*)(xs + base + 4);
  float v[8] = {a.x, a.y, a.z, a.w, b.x, b.y, b.z, b.w};
  short8 hv, lv;
#pragma unroll
  for (int i = 0; i < 8; ++i) {
    unsigned short h = f2bf(v[i]);
    hv[i] = (short)h;
    lv[i] = (short)f2bf(v[i] - bf2f(h));
  }
  *(short8*)(xh + base) = hv;
  *(short8*)(xl + base) = lv;
}

// ---------------- 256x256-tile B^T GEMM, BK=32, 8 waves, dbuf LDS.
// NOTE (R10 lesson): acc = 128 f32/thread in the unified VGPR/AGPR file;
// min-waves > 2/SIMD forces spill (5 GB scratch, MfmaUtil 7%). Keep (512,2).
// BIASMODE: 0 none, 1 row (bias[grow]), 2 col (bias[gcol], f32 add before split).
template <bool SPLIT, int BIASMODE, bool FASTA, int LGF>
__global__ __launch_bounds__(512, 2) void gemm256_kernel(
    const unsigned short* __restrict__ Aph, const unsigned short* __restrict__ Apl,
    const unsigned short* __restrict__ Bph, const unsigned short* __restrict__ Bpl,
    const float* __restrict__ bias,
    unsigned short* __restrict__ Ch, unsigned short* __restrict__ Cl,
    int lda, int ldb, int ldc)
{
  constexpr int TILES = SPLIT ? 4 : 2;
  constexpr int BUFS = TILES * 16384;
  constexpr int NP = TILES * 2;  // 16B-granule staging passes per K-tile
  __shared__ char lds[2 * BUFS];
  const int tid = threadIdx.x;
  const int wid = tid >> 6, lane = tid & 63;
  const int l = lane & 15, g = lane >> 4;
  const int wm = wid >> 2, wn = wid & 3;

  // bijective XCD-chunk swizzle (nwg % 8 == 0)
  const int nwg = gridDim.x;
  const int cpx = nwg >> 3;
  const int bid = (int)blockIdx.x;
  const int lin = (bid & 7) * cpx + (bid >> 3);
  const int tf = lin & ((1 << LGF) - 1), ts = lin >> LGF;
  const int ablk = FASTA ? tf : ts, bblk = FASTA ? ts : tf;
  const int arow0 = ablk * 256, brow0 = bblk * 256;

  // staging: pass p covers tile tp=p>>1, half h=p&1 (512 granules of 16B)
  const char* gsrc[NP];
  int ldsoff[NP];
#pragma unroll
  for (int p = 0; p < NP; ++p) {
    const int tp = p >> 1, h = p & 1;
    const int pi = h * 512 + wid * 64 + lane;
    const int row = pi >> 2;
    const int gl = (pi & 3) ^ ((row >> 1) & 3);
    const unsigned short* base =
        SPLIT ? ((tp == 0) ? Aph : (tp == 1) ? Apl : (tp == 2) ? Bph : Bpl)
              : ((tp == 0) ? Aph : Bph);
    const int r0 = (tp >= TILES / 2) ? brow0 : arow0;
    const int ld = (tp >= TILES / 2) ? ldb : lda;
    gsrc[p] = (const char*)(base + (size_t)(r0 + row) * ld + gl * 8);
    ldsoff[p] = tp * 16384 + h * 8192 + wid * 1024;
  }

  f32x4 acc[8][4];
#pragma unroll
  for (int i = 0; i < 8; ++i)
#pragma unroll
    for (int j = 0; j < 4; ++j) acc[i][j] = (f32x4){0.f, 0.f, 0.f, 0.f};

  // prologue: stage K-tile 0 into buf 0
#pragma unroll
  for (int p = 0; p < NP; ++p) gload_lds16(gsrc[p], &lds[ldsoff[p]]);
  VM0();
  BAR();

  const int nt = 32;  // K = 1024, BK = 32
#pragma unroll 1
  for (int t = 0; t < nt; ++t) {
    const int cur = (t & 1) ? BUFS : 0;
    const int nxt = BUFS - cur;
    const char* lc = lds + cur;
    const long long kadv = (long long)(t + 1) * 64;  // bytes per K-tile step

    // issue next tile's staging first (in-flight across the whole tile body)
    if (t < nt - 1) {
#pragma unroll
      for (int p = 0; p < NP; ++p) gload_lds16(gsrc[p] + kadv, &lds[nxt + ldsoff[p]]);
    }

    // flat compute on cur; compiler schedules ds_reads/MFMA interleave freely.
    short8 bh[4], bl_[4];
#pragma unroll
    for (int ni = 0; ni < 4; ++ni) {
      const int row = wn * 64 + ni * 16 + l;
      const int off = row * 64 + ((g ^ ((row >> 1) & 3)) << 4);
      bh[ni] = *(const short8*)(lc + (SPLIT ? 32768 : 16384) + off);
      if (SPLIT) bl_[ni] = *(const short8*)(lc + 49152 + off);
    }
#pragma unroll
    for (int mi = 0; mi < 8; ++mi) {
      const int row = wm * 128 + mi * 16 + l;
      const int off = row * 64 + ((g ^ ((row >> 1) & 3)) << 4);
      short8 ah = *(const short8*)(lc + off);
      short8 al_ = ah;
      if (SPLIT) al_ = *(const short8*)(lc + 16384 + off);
#pragma unroll
      for (int ni = 0; ni < 4; ++ni) {
        acc[mi][ni] = mfma16(ah, bh[ni], acc[mi][ni]);
        if (SPLIT) {
          acc[mi][ni] = mfma16(ah, bl_[ni], acc[mi][ni]);
          acc[mi][ni] = mfma16(al_, bh[ni], acc[mi][ni]);
        }
      }
    }

    VM0();  // own staging loads done; barrier makes all waves' staging visible
    BAR();
  }

#pragma unroll
  for (int mi = 0; mi < 8; ++mi)
#pragma unroll
    for (int ni = 0; ni < 4; ++ni) {
      const int gcol = brow0 + wn * 64 + ni * 16 + l;
      const int grow0v = arow0 + wm * 128 + mi * 16 + g * 4;
#pragma unroll
      for (int j = 0; j < 4; ++j) {
        const int grow = grow0v + j;
        float bv = 0.f;
        if (BIASMODE == 1) bv = bias[grow];
        if (BIASMODE == 2) bv = bias[gcol];
        float val = acc[mi][ni][j] + bv;
        unsigned short hh = f2bf(val);
        Ch[(size_t)grow * ldc + gcol] = hh;
        if (SPLIT) Cl[(size_t)grow * ldc + gcol] = f2bf(val - bf2f(hh));
      }
    }
}

// ---------------- per-window attention, 64 q-rows per block (2 blocks/window).
// Ranking/softmax score: S'_ij = Y'_i . x_j (Y' = x.G^T + wv has v_j folded in;
// remaining u_i + c terms are row-constant -> exactly invariant for top-k
// and softmax). Proven R9 structure (616 us measured).
__global__ __launch_bounds__(256, 3) void attn_kernel(
    const unsigned short* __restrict__ Yh, const unsigned short* __restrict__ Yl,
    const unsigned short* __restrict__ xbh, const unsigned short* __restrict__ xbl,
    const unsigned short* __restrict__ VT, const float* __restrict__ x,
    float* __restrict__ out, int Mc, int gr0)
{
  __shared__ char lds[49152];  // 2 QK bufs @0/24576; later P @0..16K, V bufs @16384/32768
  const int tid = threadIdx.x;
  const int wid = tid >> 6, lane = tid & 63;
  const int l = lane & 15, g = lane >> 4;
  const int nblk = (int)gridDim.x;  // multiple of 8
  const int bid = (int)blockIdx.x;
  const int lin = (bid & 7) * (nblk >> 3) + (bid >> 3);
  const int winid = lin >> 1, qhalf = lin & 1;
  const int qrow0 = winid * 128 + qhalf * 64;
  const int krow0 = winid * 128;

  // ---- QK staging: buf = 24KB {Yh@0(4K), Yl@4K, Kh@8K(8K), Kl@16K(8K)}
  const char* gsrc[6];
  int ldsoff[6];
  {
    const int rq = tid >> 2;
    const int slq = (tid & 3) ^ ((rq >> 1) & 3);
    gsrc[0] = (const char*)(Yh + (size_t)(qrow0 + rq) * 1024 + slq * 8);
    gsrc[1] = (const char*)(Yl + (size_t)(qrow0 + rq) * 1024 + slq * 8);
    ldsoff[0] = tid * 16;
    ldsoff[1] = 4096 + tid * 16;
#pragma unroll
    for (int kp = 0; kp < 2; ++kp) {
      const int r = kp * 64 + (tid >> 2);
      const int sl = (tid & 3) ^ ((r >> 1) & 3);
      gsrc[2 + kp] = (const char*)(xbh + (size_t)(krow0 + r) * 1024 + sl * 8);
      gsrc[4 + kp] = (const char*)(xbl + (size_t)(krow0 + r) * 1024 + sl * 8);
      ldsoff[2 + kp] = 8192 + (kp * 256 + tid) * 16;
      ldsoff[4 + kp] = 16384 + (kp * 256 + tid) * 16;
    }
  }

  f32x4 acc[8];
#pragma unroll
  for (int ni = 0; ni < 8; ++ni) acc[ni] = (f32x4){0.f, 0.f, 0.f, 0.f};

  // prologue: issue tile 0 into buf 0
#pragma unroll
  for (int p = 0; p < 6; ++p) gload_lds16(gsrc[p], lds + ldsoff[p]);

  const int qrow = wid * 16 + l;
  const int qoff = qrow * 64 + ((g ^ ((qrow >> 1) & 3)) << 4);

#pragma unroll 1
  for (int t = 0; t < 32; ++t) {
    __syncthreads();  // vmcnt(0) drain (tile t's loads, issued one tile ago) + barrier
    if (t < 31) {
      const long long adv = (long long)(t + 1) * 64;
      const int nb = ((t + 1) & 1) * 24576;
#pragma unroll
      for (int p = 0; p < 6; ++p) gload_lds16(gsrc[p] + adv, lds + nb + ldsoff[p]);
    }
    const char* cbuf = lds + (t & 1) * 24576;
    const short8 qhv = *(const short8*)(cbuf + qoff);
    const short8 qlv = *(const short8*)(cbuf + 4096 + qoff);
#pragma unroll
    for (int ni = 0; ni < 8; ++ni) {
      const int krow = ni * 16 + l;
      const int koff = krow * 64 + ((g ^ ((krow >> 1) & 3)) << 4);
      const short8 khv = *(const short8*)(cbuf + 8192 + koff);
      const short8 klv = *(const short8*)(cbuf + 16384 + koff);
      acc[ni] = mfma16(qhv, khv, acc[ni]);
      acc[ni] = mfma16(qhv, klv, acc[ni]);
      acc[ni] = mfma16(qlv, khv, acc[ni]);
    }
  }
  __syncthreads();  // all waves done with last QK tile -> bufs reusable

  // ---- V staging setup (dbuf 16KB chunks: 128h x 64m)
  const char* vsrc[4];
  int vdst[4];
#pragma unroll
  for (int p = 0; p < 4; ++p) {
    const int gix = p * 256 + tid;
    const int vh = gix >> 3, vsl = gix & 7;
    const int vmg = vsl ^ (vh & 7);
    vsrc[p] = (const char*)(VT + (size_t)vh * Mc + krow0 + vmg * 8);
    vdst[p] = gix * 16;
  }
  const long long hstep = (long long)Mc * 256;  // bytes per hc step (128 VT rows)

  // pre-issue V chunk 0 (hidden under top-k)
#pragma unroll
  for (int p = 0; p < 4; ++p) gload_lds16(vsrc[p], lds + 16384 + vdst[p]);

  // ---- exact top-32 + softmax
  const float s_scale = 1.0f / 32.0f;
  float vc[4][8];
  float rmax[4], ssum[4];
  unsigned int sel[4];
#pragma unroll
  for (int j = 0; j < 4; ++j) {
#pragma unroll
    for (int ni = 0; ni < 8; ++ni) vc[j][ni] = acc[ni][j] * s_scale;
    ssum[j] = 0.f;
    sel[j] = 0u;
    rmax[j] = 0.f;
  }
#pragma unroll 1
  for (int t = 0; t < 32; ++t) {
#pragma unroll
    for (int j = 0; j < 4; ++j) {
      float bv = vc[j][0];
      int bi = 0;
#pragma unroll
      for (int i = 1; i < 8; ++i)
        if (vc[j][i] > bv) { bv = vc[j][i]; bi = i; }
      float cv = bv;
      int cc = (bi << 4) | l;  // col = (bi<<4)|l; ties -> min col (matches lax.top_k)
      dpp_step<0xB1>(cv, cc);   // quad_perm(1,0,3,2): xor 1
      dpp_step<0x4E>(cv, cc);   // quad_perm(2,3,0,1): xor 2
      dpp_step<0x141>(cv, cc);  // row_half_mirror
      dpp_step<0x140>(cv, cc);  // row_mirror
      if (t == 0) rmax[j] = cv;
      ssum[j] += __expf(cv - rmax[j]);
      const bool hit = ((cc & 15) == l);
      const int ci = cc >> 4;
#pragma unroll
      for (int i = 0; i < 8; ++i)
        if (hit && ci == i) vc[j][i] = -__builtin_inff();
      sel[j] |= (hit ? (1u << ci) : 0u);
    }
  }
  // P store (bf16, swizzled) into lds[0..16K) — overwrites QK buf0 (done)
#pragma unroll
  for (int j = 0; j < 4; ++j) {
    const int qr = wid * 16 + g * 4 + j;
    const float isum = 1.0f / ssum[j];
#pragma unroll
    for (int ni = 0; ni < 8; ++ni) {
      const float p =
          ((sel[j] >> ni) & 1u) ? (__expf(acc[ni][j] * s_scale - rmax[j]) * isum) : 0.0f;
      const int col = ni * 16 + l;
      const int addr = qr * 256 + ((col * 2) ^ ((qr & 7) << 4));
      *(unsigned short*)(lds + addr) = f2bf(p);
    }
  }

  // ---- phase 2: out = P @ V over 16 chunks (8 hc x 2 mc); wave owns 32 h per chunk.
  f32x4 a2[4][2];
#pragma unroll 1
  for (int c = 0; c < 16; ++c) {
    __syncthreads();  // drains chunk c's stage (issued one chunk ago) + flushes P (c==0)
    if (c < 15) {
      const int c1 = c + 1;
      const long long soff = (long long)(c1 >> 1) * hstep + (c1 & 1) * 128;
      const int nb = 16384 + (c1 & 1) * 16384;
#pragma unroll
      for (int p = 0; p < 4; ++p) gload_lds16(vsrc[p] + soff, lds + nb + vdst[p]);
    }
    const int mc = c & 1;
    const char* vbb = lds + 16384 + mc * 16384;
    if (mc == 0) {
#pragma unroll
      for (int i = 0; i < 4; ++i)
#pragma unroll
        for (int j = 0; j < 2; ++j) a2[i][j] = (f32x4){0.f, 0.f, 0.f, 0.f};
    }
#pragma unroll
    for (int ks = 0; ks < 2; ++ks) {
      short8 pa[4];
#pragma unroll
      for (int mi = 0; mi < 4; ++mi) {
        const int q = mi * 16 + l;
        pa[mi] = *(const short8*)(lds + q * 256 +
                                  ((mc * 128 + ks * 64 + g * 16) ^ ((q & 7) << 4)));
      }
#pragma unroll
      for (int ni = 0; ni < 2; ++ni) {
        const int hl = wid * 32 + ni * 16 + l;
        const short8 vb =
            *(const short8*)(vbb + hl * 128 + ((ks * 64 + g * 16) ^ ((hl & 7) << 4)));
#pragma unroll
        for (int mi = 0; mi < 4; ++mi) a2[mi][ni] = mfma16(pa[mi], vb, a2[mi][ni]);
      }
    }
    if (mc == 1) {
      const int hc = c >> 1;
#pragma unroll
      for (int mi = 0; mi < 4; ++mi)
#pragma unroll
        for (int ni = 0; ni < 2; ++ni) {
          const int h = hc * 128 + wid * 32 + ni * 16 + l;
#pragma unroll
          for (int jj = 0; jj < 4; ++jj) {
            const int q = mi * 16 + g * 4 + jj;
            float o = a2[mi][ni][jj];
            o = (o >= 0.f) ? o : 0.01f * o;
            const size_t gi = (size_t)(gr0 + qrow0 + q) * 1024 + h;
            out[gi] = o + x[gi];
          }
        }
    }
  }
}

// ---------------- row LayerNorm in-place on d_out
__global__ __launch_bounds__(256) void ln_kernel(
    float* __restrict__ out, const float* __restrict__ gamma, const float* __restrict__ beta)
{
  const int row = blockIdx.x;
  float* p = out + (size_t)row * 1024;
  const int tidx = threadIdx.x;
  float4 v = *((const float4*)p + tidx);
  float s = v.x + v.y + v.z + v.w;
  float s2 = v.x * v.x + v.y * v.y + v.z * v.z + v.w * v.w;
#pragma unroll
  for (int st = 0; st < 6; ++st) {
    const int mk = 1 << st;
    s += __shfl_xor(s, mk, 64);
    s2 += __shfl_xor(s2, mk, 64);
  }
  __shared__ float red[8];
  const int wid = tidx >> 6, lane = tidx & 63;
  if (lane == 0) { red[wid] = s; red[4 + wid] = s2; }
  __syncthreads();
  s = red[0] + red[1] + red[2] + red[3];
  s2 = red[4] + red[5] + red[6] + red[7];
  const float mu = s * (1.0f / 1024.0f);
  float var = s2 * (1.0f / 1024.0f) - mu * mu;
  var = var < 0.f ? 0.f : var;
  const float rstd = 1.0f / sqrtf(var + 1e-5f);
  float4 gm = *((const float4*)gamma + tidx);
  float4 bt = *((const float4*)beta + tidx);
  v.x = (v.x - mu) * rstd * gm.x + bt.x;
  v.y = (v.y - mu) * rstd * gm.y + bt.y;
  v.z = (v.z - mu) * rstd * gm.z + bt.z;
  v.w = (v.w - mu) * rstd * gm.w + bt.w;
  *((float4*)p + tidx) = v;
}

extern "C" void kernel_launch(void* const* d_in, const int* in_sizes, int n_in,
                              void* d_out, int out_size, void* d_ws, size_t ws_size,
                              hipStream_t stream)
{
  (void)in_sizes; (void)n_in; (void)out_size;
  const float* x = (const float*)d_in[0];
  const float* Wq = (const float*)d_in[1];
  const float* bq = (const float*)d_in[2];
  const float* Wk = (const float*)d_in[3];
  const float* bk = (const float*)d_in[4];
  (void)bk;
  const float* Wv = (const float*)d_in[5];
  const float* bv = (const float*)d_in[6];
  const float* gamma = (const float*)d_in[7];
  const float* beta = (const float*)d_in[8];
  float* out = (float*)d_out;

  char* ws = (char*)d_ws;
  size_t off = 0;
  auto alloc = [&](size_t n) {
    char* p = ws + off;
    off = (off + n + 255) & ~(size_t)255;
    return p;
  };
  unsigned short* Wvh = (unsigned short*)alloc(1024ull * 1024 * 2);
  float* Gt = (float*)alloc(1024ull * 1024 * 4);
  unsigned short* Gth = (unsigned short*)alloc(1024ull * 1024 * 2);
  unsigned short* Gtl = (unsigned short*)alloc(1024ull * 1024 * 2);
  float* wv = (float*)alloc(1024 * 4);
  const size_t fixed = off;
  const size_t perBatch = 4096ull * 1024 * 2 * 5;  // xh,xl,Yh,Yl,VT per 4096 rows
  int NB = 8;
  while (NB > 1 && fixed + (size_t)NB * perBatch + 8192 > ws_size) NB >>= 1;
  const int M = NB * 4096;
  unsigned short* xh = (unsigned short*)alloc((size_t)M * 1024 * 2);
  unsigned short* xl = (unsigned short*)alloc((size_t)M * 1024 * 2);
  unsigned short* Yh = (unsigned short*)alloc((size_t)M * 1024 * 2);
  unsigned short* Yl = (unsigned short*)alloc((size_t)M * 1024 * 2);
  unsigned short* VT = (unsigned short*)alloc((size_t)M * 1024 * 2);

  hipLaunchKernelGGL(conv_wv_kernel, dim3(512), dim3(256), 0, stream, Wv, Wvh);
  hipLaunchKernelGGL(wv_kernel, dim3(4), dim3(256), 0, stream, Wk, bq, wv);
  hipLaunchKernelGGL(gt_kernel, dim3(16, 16), dim3(256), 0, stream, Wq, Wk, Gt);
  hipLaunchKernelGGL(gsplit_kernel, dim3(512), dim3(256), 0, stream, Gt, Gth, Gtl);
  for (int c = 0; c < 8 / NB; ++c) {
    const int r0 = c * M;
    hipLaunchKernelGGL(conv_x_kernel, dim3(M / 2), dim3(256), 0, stream,
                       x + (size_t)r0 * 1024, xh, xl);
    // Y' = x . Gt^T + wv (col bias, f32 add before split)
    hipLaunchKernelGGL((gemm256_kernel<true, 2, false, 2>), dim3((M / 256) * 4), dim3(512), 0,
                       stream, xh, xl, Gth, Gtl, wv, Yh, Yl, 1024, 1024, 1024);
    // V^T: A = Wvh (1024 x 1024), B = xh (M x 1024), C = VT (1024 x M)
    hipLaunchKernelGGL((gemm256_kernel<false, 1, true, 2>), dim3(4 * (M / 256)), dim3(512), 0,
                       stream, Wvh, (const unsigned short*)nullptr, xh,
                       (const unsigned short*)nullptr, bv, VT, (unsigned short*)nullptr,
                       1024, 1024, M);
    hipLaunchKernelGGL(attn_kernel, dim3(M / 64), dim3(256), 0, stream,
                       Yh, Yl, xh, xl, VT, x, out, M, r0);
  }
  hipLaunchKernelGGL(ln_kernel, dim3(32768), dim3(256), 0, stream, out, gamma, beta);
}